// Round 2
// baseline (381.153 us; speedup 1.0000x reference)
//
#include <hip/hip_runtime.h>
#include <hip/hip_bf16.h>

// Problem constants (B,T,S,D = 32,1024,1024,512)
#define B_ 32
#define T_ 1024
#define S_ 1024
#define D_ 512
#define M_ (B_*T_)       // 32768 GEMM rows
#define N_ D_            // 512  GEMM cols
#define K_ (2*D_)        // 1024 GEMM reduction

typedef __attribute__((ext_vector_type(8))) short bf16x8;  // 8 bf16 = 4 VGPRs
typedef __attribute__((ext_vector_type(4))) float f32x4;

__device__ inline unsigned short f2bf(float x) {
    union { float f; unsigned u; } v; v.f = x;
    unsigned r = v.u + 0x7FFFu + ((v.u >> 16) & 1u);   // RNE
    return (unsigned short)(r >> 16);
}

// ---------------------------------------------------------------------------
// Kernel 1: alignment scan -> jbuf only.
// cond (src_len >= i - inserted) is provably always true for T<=S, so
// inserted == inclusive prefix sum of isin(tok,{1,2}) over positions 1..t.
// One wave per batch; wave-64 shuffle scan.
// ---------------------------------------------------------------------------
__global__ void align_kernel(const int* __restrict__ iv, int* __restrict__ jbuf) {
    const int b = blockIdx.x;          // 32 blocks x 64 threads
    const int lane = threadIdx.x;      // 16 tokens per lane
    const int* row = iv + b * T_;
    int f[16];
    int local = 0;
    const int t0 = lane * 16;
    #pragma unroll
    for (int q = 0; q < 16; ++q) {
        const int t = t0 + q;
        const int tok = row[t];
        const int fl = (t > 0 && (tok == 1 || tok == 2)) ? 1 : 0;
        f[q] = fl;
        local += fl;
    }
    int incl = local;
    #pragma unroll
    for (int off = 1; off < 64; off <<= 1) {
        const int up = __shfl_up(incl, off, 64);
        if (lane >= off) incl += up;
    }
    int run = incl - local;            // exclusive prefix at this lane's first token
    #pragma unroll
    for (int q = 0; q < 16; ++q) {
        const int t = t0 + q;
        run += f[q];
        int j;
        if (t == 0) {
            j = 0;                     // attn[b,0,0] = 1 always
        } else {
            j = t - run - 1;
            if (j < 0) j += S_;        // torch negative-index wrap
        }
        jbuf[b * T_ + t] = j;
    }
}

// ---------------------------------------------------------------------------
// Kernel 2: attn = one_hot(j) fused zero+write, one block per [b,t] row.
// Thread i stores float4 at col 4i with the 1.0 folded in. 134 MB streamed.
// ---------------------------------------------------------------------------
__global__ __launch_bounds__(256)
void attn_fill(const int* __restrict__ jbuf, float* __restrict__ attn) {
    const int row = blockIdx.x;              // 0..M_-1
    const int j = jbuf[row];                 // scalar broadcast
    const int c4 = threadIdx.x;              // 0..255 (S_/4)
    f32x4 v = {0.f, 0.f, 0.f, 0.f};
    if ((j >> 2) == c4) v[j & 3] = 1.0f;
    ((f32x4*)(attn + (size_t)row * S_))[c4] = v;
}

// ---------------------------------------------------------------------------
// Kernel 3: W [512,1024] f32 -> bf16
// ---------------------------------------------------------------------------
__global__ void pack_w(const float* __restrict__ W, unsigned short* __restrict__ Wbf) {
    const int idx = blockIdx.x * blockDim.x + threadIdx.x;   // N_*K_/8 threads
    const f32x4 a = ((const f32x4*)W)[idx * 2];
    const f32x4 c = ((const f32x4*)W)[idx * 2 + 1];
    union { bf16x8 v; unsigned short u[8]; } pk;
    pk.u[0] = f2bf(a[0]); pk.u[1] = f2bf(a[1]); pk.u[2] = f2bf(a[2]); pk.u[3] = f2bf(a[3]);
    pk.u[4] = f2bf(c[0]); pk.u[5] = f2bf(c[1]); pk.u[6] = f2bf(c[2]); pk.u[7] = f2bf(c[3]);
    *(bf16x8*)(Wbf + (size_t)idx * 8) = pk.v;
}

// ---------------------------------------------------------------------------
// Kernel 4: build A = [gathered context | output] in bf16, row-major [M_,K_]
// ---------------------------------------------------------------------------
__global__ void pack_a(const float* __restrict__ ctx, const float* __restrict__ outp,
                       const int* __restrict__ jbuf, unsigned short* __restrict__ Abf) {
    const int idx = blockIdx.x * blockDim.x + threadIdx.x;   // M_*K_/8 threads
    const int m  = idx >> 7;           // K_/8 = 128 chunks per row
    const int k0 = (idx & 127) * 8;
    const float* src;
    if (k0 < D_) {
        const int b = m >> 10;
        src = ctx + ((size_t)(b * S_ + jbuf[m])) * D_ + k0;   // mix = gather(context)
    } else {
        src = outp + (size_t)m * D_ + (k0 - D_);
    }
    const f32x4 a = ((const f32x4*)src)[0];
    const f32x4 c = ((const f32x4*)src)[1];
    union { bf16x8 v; unsigned short u[8]; } pk;
    pk.u[0] = f2bf(a[0]); pk.u[1] = f2bf(a[1]); pk.u[2] = f2bf(a[2]); pk.u[3] = f2bf(a[3]);
    pk.u[4] = f2bf(c[0]); pk.u[5] = f2bf(c[1]); pk.u[6] = f2bf(c[2]); pk.u[7] = f2bf(c[3]);
    *(bf16x8*)(Abf + (size_t)m * K_ + k0) = pk.v;
}

// ---------------------------------------------------------------------------
// Kernel 5: GEMM (A[M,K] bf16) x (W[N,K] bf16)^T + bias, tanh epilogue.
// m97 structure: 128x128 tile, BK=64, 4 waves, 4x4 of 16x16x32 MFMA per wave,
// global_load_lds width-16 staging. XCD-affine swizzle: the 4 bn-siblings of
// a bm are 256 apart in blockIdx -> same (blockIdx % 8) XCD -> A re-reads hit
// that XCD's L2 instead of refetching from L3/HBM.
// ---------------------------------------------------------------------------
#define BM 128
#define BN 128
#define BK 64

template <bool PACKED>
__global__ __launch_bounds__(256)
void gemm_bt_tanh(const unsigned short* __restrict__ Abf,
                  const unsigned short* __restrict__ Wbf,
                  const float* __restrict__ bias,
                  float* __restrict__ out,
                  const float* __restrict__ ctx,
                  const float* __restrict__ outp,
                  const int* __restrict__ jbuf) {
    __shared__ unsigned short As[BM * BK];   // 16 KB, row-major [row][k]
    __shared__ unsigned short Bs[BN * BK];   // 16 KB, row-major [n][k]

    const int tid  = threadIdx.x;
    const int lane = tid & 63;
    const int wave = tid >> 6;
    const int wm = wave >> 1, wn = wave & 1;     // 2x2 waves -> 64x64 each
    const int l16 = lane & 15, quad = lane >> 4;

    const int bm = blockIdx.x & 255;             // 256 m-tiles (XCD-affine)
    const int bn = blockIdx.x >> 8;              // 4 n-tiles
    const int mBase = bm * BM;
    const int nBase = bn * BN;

    f32x4 acc[4][4] = {};

    for (int ko = 0; ko < K_; ko += BK) {
        // ---- stage A (128x64) and B (128x64), 1024 16B-chunks each /256 thr
        #pragma unroll
        for (int it = 0; it < 4; ++it) {
            const int chunk = it * 256 + tid;        // lane-consecutive
            const int row = chunk >> 3;              // 0..127
            const int k8  = (chunk & 7) * 8;
            if (PACKED) {
                const unsigned short* gA = Abf + (size_t)(mBase + row) * K_ + ko + k8;
                __builtin_amdgcn_global_load_lds(
                    (const __attribute__((address_space(1))) void*)gA,
                    (__attribute__((address_space(3))) void*)(As + chunk * 8), 16, 0, 0);
            } else {
                const int kg = ko + k8;
                const int m = mBase + row;
                const float* src;
                if (kg < D_) {
                    const int b = m >> 10;
                    src = ctx + ((size_t)(b * S_ + jbuf[m])) * D_ + kg;
                } else {
                    src = outp + (size_t)m * D_ + (kg - D_);
                }
                const f32x4 a = ((const f32x4*)src)[0];
                const f32x4 c = ((const f32x4*)src)[1];
                union { bf16x8 v; unsigned short u[8]; } pk;
                pk.u[0]=f2bf(a[0]); pk.u[1]=f2bf(a[1]); pk.u[2]=f2bf(a[2]); pk.u[3]=f2bf(a[3]);
                pk.u[4]=f2bf(c[0]); pk.u[5]=f2bf(c[1]); pk.u[6]=f2bf(c[2]); pk.u[7]=f2bf(c[3]);
                *(bf16x8*)(As + chunk * 8) = pk.v;
            }
        }
        #pragma unroll
        for (int it = 0; it < 4; ++it) {
            const int chunk = it * 256 + tid;
            const int row = chunk >> 3;
            const int k8  = (chunk & 7) * 8;
            const unsigned short* gB = Wbf + (size_t)(nBase + row) * K_ + ko + k8;
            __builtin_amdgcn_global_load_lds(
                (const __attribute__((address_space(1))) void*)gB,
                (__attribute__((address_space(3))) void*)(Bs + chunk * 8), 16, 0, 0);
        }
        __syncthreads();

        // ---- 2 K-steps of 32; 16 MFMA each
        #pragma unroll
        for (int ks = 0; ks < 2; ++ks) {
            bf16x8 af[4], bfr[4];
            #pragma unroll
            for (int mt = 0; mt < 4; ++mt)
                af[mt] = *(const bf16x8*)&As[(wm * 64 + mt * 16 + l16) * BK + ks * 32 + quad * 8];
            #pragma unroll
            for (int nt = 0; nt < 4; ++nt)
                bfr[nt] = *(const bf16x8*)&Bs[(wn * 64 + nt * 16 + l16) * BK + ks * 32 + quad * 8];
            #pragma unroll
            for (int mt = 0; mt < 4; ++mt)
                #pragma unroll
                for (int nt = 0; nt < 4; ++nt)
                    acc[mt][nt] = __builtin_amdgcn_mfma_f32_16x16x32_bf16(
                        af[mt], bfr[nt], acc[mt][nt], 0, 0, 0);
        }
        __syncthreads();
    }

    // ---- epilogue: tanh(acc + bias), fp32 store
    #pragma unroll
    for (int nt = 0; nt < 4; ++nt) {
        const int n = nBase + wn * 64 + nt * 16 + l16;
        const float bv = bias[n];
        #pragma unroll
        for (int mt = 0; mt < 4; ++mt) {
            #pragma unroll
            for (int r = 0; r < 4; ++r) {
                const int m = mBase + wm * 64 + mt * 16 + quad * 4 + r;
                out[(size_t)m * N_ + n] = tanhf(acc[mt][nt][r] + bv);
            }
        }
    }
}

// ---------------------------------------------------------------------------
extern "C" void kernel_launch(void* const* d_in, const int* in_sizes, int n_in,
                              void* d_out, int out_size, void* d_ws, size_t ws_size,
                              hipStream_t stream) {
    const int*   iv   = (const int*)d_in[0];    // input_var [B,T]
    const float* outp = (const float*)d_in[1];  // output   [B,T,D]
    const float* ctx  = (const float*)d_in[2];  // context  [B,S,D]
    // d_in[3] = di (unused by reference body)
    const float* W    = (const float*)d_in[4];  // [D, 2D]
    const float* bias = (const float*)d_in[5];  // [D]

    float* out  = (float*)d_out;                       // [B,T,D]
    float* attn = out + (size_t)M_ * N_;               // [B,T,S]

    // workspace layout: j[M_] int32 | Wbf[N_*K_] bf16 | Abf[M_*K_] bf16
    int* jbuf = (int*)d_ws;
    unsigned short* Wbf = (unsigned short*)((char*)d_ws + (size_t)M_ * 4);
    unsigned short* Abf = (unsigned short*)((char*)d_ws + (size_t)M_ * 4 + (size_t)N_ * K_ * 2);
    const size_t need_full = (size_t)M_ * 4 + (size_t)N_ * K_ * 2 + (size_t)M_ * K_ * 2;

    align_kernel<<<B_, 64, 0, stream>>>(iv, jbuf);
    attn_fill<<<M_, 256, 0, stream>>>(jbuf, attn);
    pack_w<<<(N_ * K_ / 8) / 256, 256, 0, stream>>>(W, Wbf);

    if (ws_size >= need_full) {
        pack_a<<<(M_ * K_ / 8) / 256, 256, 0, stream>>>(ctx, outp, jbuf, Abf);
        gemm_bt_tanh<true><<<(M_ / BM) * (N_ / BN), 256, 0, stream>>>(
            Abf, Wbf, bias, out, ctx, outp, jbuf);
    } else {
        gemm_bt_tanh<false><<<(M_ / BM) * (N_ / BN), 256, 0, stream>>>(
            Abf, Wbf, bias, out, ctx, outp, jbuf);
    }
}

// Round 3
// 379.801 us; speedup vs baseline: 1.0036x; 1.0036x over previous
//
#include <hip/hip_runtime.h>
#include <hip/hip_bf16.h>

// Problem constants (B,T,S,D = 32,1024,1024,512)
#define B_ 32
#define T_ 1024
#define S_ 1024
#define D_ 512
#define M_ (B_*T_)       // 32768 GEMM rows
#define N_ D_            // 512  GEMM cols
#define K_ (2*D_)        // 1024 GEMM reduction

typedef __attribute__((ext_vector_type(8))) short bf16x8;  // 8 bf16 = 4 VGPRs
typedef __attribute__((ext_vector_type(4))) float f32x4;

__device__ inline unsigned short f2bf(float x) {
    union { float f; unsigned u; } v; v.f = x;
    unsigned r = v.u + 0x7FFFu + ((v.u >> 16) & 1u);   // RNE
    return (unsigned short)(r >> 16);
}

// fast tanh: 1 - 2/(e^{2x}+1) via hw exp2 + rcp. rel err ~1e-7, exact sat at +-1.
__device__ inline float fast_tanh(float x) {
#if __has_builtin(__builtin_amdgcn_exp2f) && __has_builtin(__builtin_amdgcn_rcpf)
    const float e = __builtin_amdgcn_exp2f(x * 2.885390082f);   // e^{2x}
    const float r = __builtin_amdgcn_rcpf(e + 1.0f);
    return 1.0f - 2.0f * r;
#else
    return tanhf(x);
#endif
}

// ---------------------------------------------------------------------------
// Kernel 1: alignment scan -> jbuf.
// cond (src_len >= i - inserted) is provably always true for T<=S, so
// inserted == inclusive prefix sum of isin(tok,{1,2}) over positions 1..t.
// ---------------------------------------------------------------------------
__global__ void align_kernel(const int* __restrict__ iv, int* __restrict__ jbuf) {
    const int b = blockIdx.x;          // 32 blocks x 64 threads
    const int lane = threadIdx.x;      // 16 tokens per lane
    const int* row = iv + b * T_;
    int f[16];
    int local = 0;
    const int t0 = lane * 16;
    #pragma unroll
    for (int q = 0; q < 16; ++q) {
        const int t = t0 + q;
        const int tok = row[t];
        const int fl = (t > 0 && (tok == 1 || tok == 2)) ? 1 : 0;
        f[q] = fl;
        local += fl;
    }
    int incl = local;
    #pragma unroll
    for (int off = 1; off < 64; off <<= 1) {
        const int up = __shfl_up(incl, off, 64);
        if (lane >= off) incl += up;
    }
    int run = incl - local;            // exclusive prefix at this lane's first token
    #pragma unroll
    for (int q = 0; q < 16; ++q) {
        const int t = t0 + q;
        run += f[q];
        int j;
        if (t == 0) {
            j = 0;                     // attn[b,0,0] = 1 always
        } else {
            j = t - run - 1;
            if (j < 0) j += S_;        // torch negative-index wrap
        }
        jbuf[b * T_ + t] = j;
    }
}

// ---------------------------------------------------------------------------
// Kernel 2: W [512,1024] f32 -> bf16
// ---------------------------------------------------------------------------
__global__ void pack_w(const float* __restrict__ W, unsigned short* __restrict__ Wbf) {
    const int idx = blockIdx.x * blockDim.x + threadIdx.x;   // N_*K_/8 threads
    const f32x4 a = ((const f32x4*)W)[idx * 2];
    const f32x4 c = ((const f32x4*)W)[idx * 2 + 1];
    union { bf16x8 v; unsigned short u[8]; } pk;
    pk.u[0] = f2bf(a[0]); pk.u[1] = f2bf(a[1]); pk.u[2] = f2bf(a[2]); pk.u[3] = f2bf(a[3]);
    pk.u[4] = f2bf(c[0]); pk.u[5] = f2bf(c[1]); pk.u[6] = f2bf(c[2]); pk.u[7] = f2bf(c[3]);
    *(bf16x8*)(Wbf + (size_t)idx * 8) = pk.v;
}

// ---------------------------------------------------------------------------
// Kernel 3: fused A-pack + attn one-hot. One block per 2 rows (256 threads).
//   pack: thread (r=tid>>7, kc=tid&127) converts 8 elems of row m0+r.
//   attn: thread writes f32x4 col-chunk tid for both rows, 1.0 folded in.
// ---------------------------------------------------------------------------
__global__ __launch_bounds__(256)
void pack_a_attn(const float* __restrict__ ctx, const float* __restrict__ outp,
                 const int* __restrict__ jbuf, unsigned short* __restrict__ Abf,
                 float* __restrict__ attn) {
    const int m0 = blockIdx.x * 2;
    const int tid = threadIdx.x;
    const int r  = tid >> 7;
    const int kc = tid & 127;
    const int m  = m0 + r;
    const int k0 = kc * 8;
    const int j0 = jbuf[m0];
    const int j1 = jbuf[m0 + 1];

    // ---- pack 8 elems
    const int jm = r ? j1 : j0;
    const float* src;
    if (k0 < D_) {
        const int b = m >> 10;
        src = ctx + ((size_t)(b * S_ + jm)) * D_ + k0;     // mix = gather(context)
    } else {
        src = outp + (size_t)m * D_ + (k0 - D_);
    }
    const f32x4 a = ((const f32x4*)src)[0];
    const f32x4 c = ((const f32x4*)src)[1];
    union { bf16x8 v; unsigned short u[8]; } pk;
    pk.u[0] = f2bf(a[0]); pk.u[1] = f2bf(a[1]); pk.u[2] = f2bf(a[2]); pk.u[3] = f2bf(a[3]);
    pk.u[4] = f2bf(c[0]); pk.u[5] = f2bf(c[1]); pk.u[6] = f2bf(c[2]); pk.u[7] = f2bf(c[3]);
    *(bf16x8*)(Abf + (size_t)m * K_ + k0) = pk.v;

    // ---- attn rows m0, m0+1 (S_/4 = 256 chunks each)
    f32x4 v0 = {0.f, 0.f, 0.f, 0.f};
    f32x4 v1 = {0.f, 0.f, 0.f, 0.f};
    if ((j0 >> 2) == tid) v0[j0 & 3] = 1.0f;
    if ((j1 >> 2) == tid) v1[j1 & 3] = 1.0f;
    ((f32x4*)(attn + (size_t)m0 * S_))[tid] = v0;
    ((f32x4*)(attn + (size_t)(m0 + 1) * S_))[tid] = v1;
}

// ---------------------------------------------------------------------------
// Kernel 4: GEMM (A[M,K] bf16) x (W[N,K] bf16)^T + bias, fast-tanh epilogue.
// 128x128 tile, BK=64, 4 waves, 4x4 of 16x16x32 MFMA per wave,
// global_load_lds width-16 staging.
//
// LDS bank-conflict fix: XOR swizzle. Global k-chunk q (8 bf16 = 16B) of tile
// row r is stored in LDS slot r*8 + (q ^ (r&7)). Staging keeps LDS dests
// lane-consecutive (global_load_lds constraint); the permutation is applied
// to the GLOBAL address (stays inside one 128B segment -> still coalesced).
// Fragment ds_read_b128: 16 lanes spread across all 8 bank-groups -> 2-way
// aliasing only (free), vs 16-way conflict of the naive row-major layout.
// ---------------------------------------------------------------------------
#define BM 128
#define BN 128
#define BK 64

template <bool PACKED>
__global__ __launch_bounds__(256)
void gemm_bt_tanh(const unsigned short* __restrict__ Abf,
                  const unsigned short* __restrict__ Wbf,
                  const float* __restrict__ bias,
                  float* __restrict__ out,
                  const float* __restrict__ ctx,
                  const float* __restrict__ outp,
                  const int* __restrict__ jbuf) {
    __shared__ unsigned short As[BM * BK];   // 16 KB
    __shared__ unsigned short Bs[BN * BK];   // 16 KB

    const int tid  = threadIdx.x;
    const int lane = tid & 63;
    const int wave = tid >> 6;
    const int wm = wave >> 1, wn = wave & 1;     // 2x2 waves -> 64x64 each
    const int l16 = lane & 15, quad = lane >> 4;

    const int bm = blockIdx.x & 255;             // 256 m-tiles (XCD-affine)
    const int bn = blockIdx.x >> 8;              // 4 n-tiles
    const int mBase = bm * BM;
    const int nBase = bn * BN;

    f32x4 acc[4][4] = {};

    for (int ko = 0; ko < K_; ko += BK) {
        #pragma unroll
        for (int it = 0; it < 4; ++it) {
            const int chunk = it * 256 + tid;        // LDS slot, lane-consecutive
            const int row = chunk >> 3;              // 0..127
            const int kc  = chunk & 7;
            const int gk8 = (kc ^ (row & 7)) * 8;    // swizzled global k-offset
            if (PACKED) {
                const unsigned short* gA = Abf + (size_t)(mBase + row) * K_ + ko + gk8;
                __builtin_amdgcn_global_load_lds(
                    (const __attribute__((address_space(1))) void*)gA,
                    (__attribute__((address_space(3))) void*)(As + chunk * 8), 16, 0, 0);
            } else {
                const int kg = ko + gk8;
                const int m = mBase + row;
                const float* src;
                if (kg < D_) {
                    const int b = m >> 10;
                    src = ctx + ((size_t)(b * S_ + jbuf[m])) * D_ + kg;
                } else {
                    src = outp + (size_t)m * D_ + (kg - D_);
                }
                const f32x4 a = ((const f32x4*)src)[0];
                const f32x4 c = ((const f32x4*)src)[1];
                union { bf16x8 v; unsigned short u[8]; } pk;
                pk.u[0]=f2bf(a[0]); pk.u[1]=f2bf(a[1]); pk.u[2]=f2bf(a[2]); pk.u[3]=f2bf(a[3]);
                pk.u[4]=f2bf(c[0]); pk.u[5]=f2bf(c[1]); pk.u[6]=f2bf(c[2]); pk.u[7]=f2bf(c[3]);
                *(bf16x8*)(As + chunk * 8) = pk.v;
            }
        }
        #pragma unroll
        for (int it = 0; it < 4; ++it) {
            const int chunk = it * 256 + tid;
            const int row = chunk >> 3;
            const int kc  = chunk & 7;
            const int gk8 = (kc ^ (row & 7)) * 8;
            const unsigned short* gB = Wbf + (size_t)(nBase + row) * K_ + ko + gk8;
            __builtin_amdgcn_global_load_lds(
                (const __attribute__((address_space(1))) void*)gB,
                (__attribute__((address_space(3))) void*)(Bs + chunk * 8), 16, 0, 0);
        }
        __syncthreads();

        // ---- 2 K-steps of 32; 16 MFMA each
        #pragma unroll
        for (int ks = 0; ks < 2; ++ks) {
            bf16x8 af[4], bfr[4];
            #pragma unroll
            for (int mt = 0; mt < 4; ++mt) {
                const int r = wm * 64 + mt * 16 + l16;
                const int q = ks * 4 + quad;                 // k-chunk wanted
                af[mt] = *(const bf16x8*)&As[(r * 8 + (q ^ (r & 7))) * 8];
            }
            #pragma unroll
            for (int nt = 0; nt < 4; ++nt) {
                const int r = wn * 64 + nt * 16 + l16;
                const int q = ks * 4 + quad;
                bfr[nt] = *(const bf16x8*)&Bs[(r * 8 + (q ^ (r & 7))) * 8];
            }
            #pragma unroll
            for (int mt = 0; mt < 4; ++mt)
                #pragma unroll
                for (int nt = 0; nt < 4; ++nt)
                    acc[mt][nt] = __builtin_amdgcn_mfma_f32_16x16x32_bf16(
                        af[mt], bfr[nt], acc[mt][nt], 0, 0, 0);
        }
        __syncthreads();
    }

    // ---- epilogue: fast_tanh(acc + bias), fp32 store
    #pragma unroll
    for (int nt = 0; nt < 4; ++nt) {
        const int n = nBase + wn * 64 + nt * 16 + l16;
        const float bv = bias[n];
        #pragma unroll
        for (int mt = 0; mt < 4; ++mt) {
            #pragma unroll
            for (int r = 0; r < 4; ++r) {
                const int m = mBase + wm * 64 + mt * 16 + quad * 4 + r;
                out[(size_t)m * N_ + n] = fast_tanh(acc[mt][nt][r] + bv);
            }
        }
    }
}

// ---------------------------------------------------------------------------
extern "C" void kernel_launch(void* const* d_in, const int* in_sizes, int n_in,
                              void* d_out, int out_size, void* d_ws, size_t ws_size,
                              hipStream_t stream) {
    const int*   iv   = (const int*)d_in[0];    // input_var [B,T]
    const float* outp = (const float*)d_in[1];  // output   [B,T,D]
    const float* ctx  = (const float*)d_in[2];  // context  [B,S,D]
    // d_in[3] = di (unused by reference body)
    const float* W    = (const float*)d_in[4];  // [D, 2D]
    const float* bias = (const float*)d_in[5];  // [D]

    float* out  = (float*)d_out;                       // [B,T,D]
    float* attn = out + (size_t)M_ * N_;               // [B,T,S]

    // workspace layout: j[M_] int32 | Wbf[N_*K_] bf16 | Abf[M_*K_] bf16
    int* jbuf = (int*)d_ws;
    unsigned short* Wbf = (unsigned short*)((char*)d_ws + (size_t)M_ * 4);
    unsigned short* Abf = (unsigned short*)((char*)d_ws + (size_t)M_ * 4 + (size_t)N_ * K_ * 2);
    const size_t need_full = (size_t)M_ * 4 + (size_t)N_ * K_ * 2 + (size_t)M_ * K_ * 2;

    align_kernel<<<B_, 64, 0, stream>>>(iv, jbuf);
    pack_w<<<(N_ * K_ / 8) / 256, 256, 0, stream>>>(W, Wbf);

    if (ws_size >= need_full) {
        pack_a_attn<<<M_ / 2, 256, 0, stream>>>(ctx, outp, jbuf, Abf, attn);
        gemm_bt_tanh<true><<<(M_ / BM) * (N_ / BN), 256, 0, stream>>>(
            Abf, Wbf, bias, out, ctx, outp, jbuf);
    } else {
        // ws-lean fallback: attn via dedicated pass, A converted inline in GEMM
        pack_a_attn<<<M_ / 2, 256, 0, stream>>>(ctx, outp, jbuf, Abf, attn); // attn only valid if ws holds Abf; if ws too small this is UB -> but need_full ~132MB is well under typical ws
        gemm_bt_tanh<false><<<(M_ / BM) * (N_ / BN), 256, 0, stream>>>(
            Abf, Wbf, bias, out, ctx, outp, jbuf);
    }
}

// Round 4
// 364.545 us; speedup vs baseline: 1.0456x; 1.0418x over previous
//
#include <hip/hip_runtime.h>
#include <hip/hip_bf16.h>

// Problem constants (B,T,S,D = 32,1024,1024,512)
#define B_ 32
#define T_ 1024
#define S_ 1024
#define D_ 512
#define M_ (B_*T_)       // 32768 GEMM rows
#define N_ D_            // 512  GEMM cols
#define K_ (2*D_)        // 1024 GEMM reduction

typedef __attribute__((ext_vector_type(8))) short bf16x8;  // 8 bf16 = 4 VGPRs
typedef __attribute__((ext_vector_type(4))) float f32x4;

__device__ inline unsigned short f2bf(float x) {
    union { float f; unsigned u; } v; v.f = x;
    unsigned r = v.u + 0x7FFFu + ((v.u >> 16) & 1u);   // RNE
    return (unsigned short)(r >> 16);
}

// pack 2 f32 -> 2 bf16 (RNE), packed in 32 bits
__device__ inline unsigned cvt2bf(float lo, float hi) {
#if __has_builtin(__builtin_amdgcn_cvt_pk_bf16_f32)
    typedef __attribute__((ext_vector_type(2))) __bf16 bf2;
    union { bf2 v; unsigned u; } r;
    r.v = __builtin_amdgcn_cvt_pk_bf16_f32(lo, hi);
    return r.u;
#else
    return (unsigned)f2bf(lo) | ((unsigned)f2bf(hi) << 16);
#endif
}

// fast tanh: 1 - 2/(e^{2x}+1) via hw exp2 + rcp. rel err ~1e-7, exact sat at +-1.
__device__ inline float fast_tanh(float x) {
#if __has_builtin(__builtin_amdgcn_exp2f) && __has_builtin(__builtin_amdgcn_rcpf)
    const float e = __builtin_amdgcn_exp2f(x * 2.885390082f);   // e^{2x}
    const float r = __builtin_amdgcn_rcpf(e + 1.0f);
    return 1.0f - 2.0f * r;
#else
    return tanhf(x);
#endif
}

// ---------------------------------------------------------------------------
// Kernel 1: alignment scan -> jbuf.
// cond (src_len >= i - inserted) is provably always true for T<=S, so
// inserted == inclusive prefix sum of isin(tok,{1,2}) over positions 1..t.
// ---------------------------------------------------------------------------
__global__ void align_kernel(const int* __restrict__ iv, int* __restrict__ jbuf) {
    const int b = blockIdx.x;          // 32 blocks x 64 threads
    const int lane = threadIdx.x;      // 16 tokens per lane
    const int* row = iv + b * T_;
    int f[16];
    int local = 0;
    const int t0 = lane * 16;
    #pragma unroll
    for (int q = 0; q < 16; ++q) {
        const int t = t0 + q;
        const int tok = row[t];
        const int fl = (t > 0 && (tok == 1 || tok == 2)) ? 1 : 0;
        f[q] = fl;
        local += fl;
    }
    int incl = local;
    #pragma unroll
    for (int off = 1; off < 64; off <<= 1) {
        const int up = __shfl_up(incl, off, 64);
        if (lane >= off) incl += up;
    }
    int run = incl - local;            // exclusive prefix at this lane's first token
    #pragma unroll
    for (int q = 0; q < 16; ++q) {
        const int t = t0 + q;
        run += f[q];
        int j;
        if (t == 0) {
            j = 0;                     // attn[b,0,0] = 1 always
        } else {
            j = t - run - 1;
            if (j < 0) j += S_;        // torch negative-index wrap
        }
        jbuf[b * T_ + t] = j;
    }
}

// ---------------------------------------------------------------------------
// Kernel 2: W [512,1024] f32 -> bf16
// ---------------------------------------------------------------------------
__global__ void pack_w(const float* __restrict__ W, unsigned short* __restrict__ Wbf) {
    const int idx = blockIdx.x * blockDim.x + threadIdx.x;   // N_*K_/8 threads
    const f32x4 a = ((const f32x4*)W)[idx * 2];
    const f32x4 c = ((const f32x4*)W)[idx * 2 + 1];
    union { bf16x8 v; unsigned u[4]; } pk;
    pk.u[0] = cvt2bf(a[0], a[1]); pk.u[1] = cvt2bf(a[2], a[3]);
    pk.u[2] = cvt2bf(c[0], c[1]); pk.u[3] = cvt2bf(c[2], c[3]);
    *(bf16x8*)(Wbf + (size_t)idx * 8) = pk.v;
}

// ---------------------------------------------------------------------------
// Kernel 3 (heterogeneous): blocks [0,1024) = GEMM tiles; [1024,1536) = attn.
//
// GEMM: out = tanh(A @ Wbf^T + bias), A built INLINE from gathered context /
// output rows (f32 -> bf16 cvt during staging) — no Abf round-trip, and no
// dependency on the attn one-hot, so attn blocks (pure streaming, no LDS,
// low VGPR) co-schedule into spare wave slots and their 134 MB write hides
// under GEMM's MFMA phase.
//
// LDS XOR swizzle (both operands): k-chunk q (8 bf16=16B) of tile row r lives
// at slot r*8 + (q ^ (r&7)) -> fragment ds_read_b128 spreads all 8 bank
// groups (2-way aliasing only). B staging keeps global_load_lds with the
// swizzle applied to the global address (stays in one 128B segment).
// ---------------------------------------------------------------------------
#define BM 128
#define BN 128
#define BK 64
#define NGEMM ((M_ / BM) * (N_ / BN))   // 1024
#define NATTN 512                        // 64 rows each

__global__ __launch_bounds__(256)
void gemm_attn(const unsigned short* __restrict__ Wbf,
               const float* __restrict__ bias,
               float* __restrict__ out,
               float* __restrict__ attn,
               const float* __restrict__ ctx,
               const float* __restrict__ outp,
               const int* __restrict__ jbuf) {
    const int bx = blockIdx.x;
    const int tid = threadIdx.x;

    if (bx >= NGEMM) {
        // ---------------- attn one-hot: 64 rows per block ----------------
        const int m0 = (bx - NGEMM) * 64;
        #pragma unroll 4
        for (int r = 0; r < 64; ++r) {
            const int row = m0 + r;
            const int j = jbuf[row];               // broadcast load
            f32x4 v = {0.f, 0.f, 0.f, 0.f};
            if ((j >> 2) == tid) v[j & 3] = 1.0f;
            ((f32x4*)(attn + (size_t)row * S_))[tid] = v;
        }
        return;
    }

    // ---------------- GEMM tile ----------------
    __shared__ unsigned short As[BM * BK];   // 16 KB
    __shared__ unsigned short Bs[BN * BK];   // 16 KB

    const int lane = tid & 63;
    const int wave = tid >> 6;
    const int wm = wave >> 1, wn = wave & 1;     // 2x2 waves -> 64x64 each
    const int l16 = lane & 15, quad = lane >> 4;

    const int bm = bx & 255;                     // 256 m-tiles (XCD-affine)
    const int bn = bx >> 8;                      // 4 n-tiles
    const int mBase = bm * BM;
    const int nBase = bn * BN;

    // A staging assignment: thread -> (row = tid>>1, 32 contiguous f32)
    const int arow = tid >> 1;                   // 0..127
    const int aseg = tid & 1;                    // which 32-f32 half of BK
    const int am   = mBase + arow;
    const int jm   = jbuf[am];                   // gather row for k < D_
    const float* actx = ctx + ((size_t)((am >> 10) * S_ + jm)) * D_ + aseg * 32;
    const float* aoutp = outp + (size_t)am * D_ - D_ + aseg * 32;  // indexed by ko>=512

    f32x4 acc[4][4] = {};

    for (int ko = 0; ko < K_; ko += BK) {
        // ---- stage A inline: 32 f32 -> 32 bf16, swizzled ds_write_b128 x4
        {
            const float* srcA = (ko < D_) ? (actx + ko) : (aoutp + ko);
            f32x4 fa[8];
            #pragma unroll
            for (int i = 0; i < 8; ++i) fa[i] = ((const f32x4*)srcA)[i];
            #pragma unroll
            for (int c = 0; c < 4; ++c) {
                union { bf16x8 v; unsigned u[4]; } pk;
                pk.u[0] = cvt2bf(fa[c*2][0],   fa[c*2][1]);
                pk.u[1] = cvt2bf(fa[c*2][2],   fa[c*2][3]);
                pk.u[2] = cvt2bf(fa[c*2+1][0], fa[c*2+1][1]);
                pk.u[3] = cvt2bf(fa[c*2+1][2], fa[c*2+1][3]);
                const int q = aseg * 4 + c;
                *(bf16x8*)&As[(arow * 8 + (q ^ (arow & 7))) * 8] = pk.v;
            }
        }
        // ---- stage B via global_load_lds (packed bf16 W)
        #pragma unroll
        for (int it = 0; it < 4; ++it) {
            const int chunk = it * 256 + tid;
            const int row = chunk >> 3;
            const int kc  = chunk & 7;
            const int gk8 = (kc ^ (row & 7)) * 8;
            const unsigned short* gB = Wbf + (size_t)(nBase + row) * K_ + ko + gk8;
            __builtin_amdgcn_global_load_lds(
                (const __attribute__((address_space(1))) void*)gB,
                (__attribute__((address_space(3))) void*)(Bs + chunk * 8), 16, 0, 0);
        }
        __syncthreads();

        // ---- 2 K-steps of 32; 16 MFMA each
        #pragma unroll
        for (int ks = 0; ks < 2; ++ks) {
            bf16x8 af[4], bfr[4];
            #pragma unroll
            for (int mt = 0; mt < 4; ++mt) {
                const int r = wm * 64 + mt * 16 + l16;
                const int q = ks * 4 + quad;
                af[mt] = *(const bf16x8*)&As[(r * 8 + (q ^ (r & 7))) * 8];
            }
            #pragma unroll
            for (int nt = 0; nt < 4; ++nt) {
                const int r = wn * 64 + nt * 16 + l16;
                const int q = ks * 4 + quad;
                bfr[nt] = *(const bf16x8*)&Bs[(r * 8 + (q ^ (r & 7))) * 8];
            }
            #pragma unroll
            for (int mt = 0; mt < 4; ++mt)
                #pragma unroll
                for (int nt = 0; nt < 4; ++nt)
                    acc[mt][nt] = __builtin_amdgcn_mfma_f32_16x16x32_bf16(
                        af[mt], bfr[nt], acc[mt][nt], 0, 0, 0);
        }
        __syncthreads();
    }

    // ---- epilogue: fast_tanh(acc + bias), fp32 store
    #pragma unroll
    for (int nt = 0; nt < 4; ++nt) {
        const int n = nBase + wn * 64 + nt * 16 + l16;
        const float bv = bias[n];
        #pragma unroll
        for (int mt = 0; mt < 4; ++mt) {
            #pragma unroll
            for (int r = 0; r < 4; ++r) {
                const int m = mBase + wm * 64 + mt * 16 + quad * 4 + r;
                out[(size_t)m * N_ + n] = fast_tanh(acc[mt][nt][r] + bv);
            }
        }
    }
}

// ---------------------------------------------------------------------------
extern "C" void kernel_launch(void* const* d_in, const int* in_sizes, int n_in,
                              void* d_out, int out_size, void* d_ws, size_t ws_size,
                              hipStream_t stream) {
    const int*   iv   = (const int*)d_in[0];    // input_var [B,T]
    const float* outp = (const float*)d_in[1];  // output   [B,T,D]
    const float* ctx  = (const float*)d_in[2];  // context  [B,S,D]
    // d_in[3] = di (unused by reference body)
    const float* W    = (const float*)d_in[4];  // [D, 2D]
    const float* bias = (const float*)d_in[5];  // [D]

    float* out  = (float*)d_out;                       // [B,T,D]
    float* attn = out + (size_t)M_ * N_;               // [B,T,S]

    // workspace layout: j[M_] int32 | Wbf[N_*K_] bf16   (~1.1 MB total)
    int* jbuf = (int*)d_ws;
    unsigned short* Wbf = (unsigned short*)((char*)d_ws + (size_t)M_ * 4);

    align_kernel<<<B_, 64, 0, stream>>>(iv, jbuf);
    pack_w<<<(N_ * K_ / 8) / 256, 256, 0, stream>>>(W, Wbf);
    gemm_attn<<<NGEMM + NATTN, 256, 0, stream>>>(Wbf, bias, out, attn, ctx, outp, jbuf);
}

// Round 5
// 360.210 us; speedup vs baseline: 1.0581x; 1.0120x over previous
//
#include <hip/hip_runtime.h>
#include <hip/hip_bf16.h>

// Problem constants (B,T,S,D = 32,1024,1024,512)
#define B_ 32
#define T_ 1024
#define S_ 1024
#define D_ 512
#define M_ (B_*T_)       // 32768 GEMM rows
#define N_ D_            // 512  GEMM cols
#define K_ (2*D_)        // 1024 GEMM reduction

typedef __attribute__((ext_vector_type(8))) short bf16x8;  // 8 bf16 = 4 VGPRs
typedef __attribute__((ext_vector_type(4))) float f32x4;

__device__ inline unsigned short f2bf(float x) {
    union { float f; unsigned u; } v; v.f = x;
    unsigned r = v.u + 0x7FFFu + ((v.u >> 16) & 1u);   // RNE
    return (unsigned short)(r >> 16);
}

// pack 2 f32 -> 2 bf16 (RNE), packed in 32 bits
__device__ inline unsigned cvt2bf(float lo, float hi) {
#if __has_builtin(__builtin_amdgcn_cvt_pk_bf16_f32)
    typedef __attribute__((ext_vector_type(2))) __bf16 bf2;
    union { bf2 v; unsigned u; } r;
    r.v = __builtin_amdgcn_cvt_pk_bf16_f32(lo, hi);
    return r.u;
#else
    return (unsigned)f2bf(lo) | ((unsigned)f2bf(hi) << 16);
#endif
}

// fast tanh: 1 - 2/(e^{2x}+1) via hw exp2 + rcp. rel err ~1e-7, exact sat at +-1.
__device__ inline float fast_tanh(float x) {
#if __has_builtin(__builtin_amdgcn_exp2f) && __has_builtin(__builtin_amdgcn_rcpf)
    const float e = __builtin_amdgcn_exp2f(x * 2.885390082f);   // e^{2x}
    const float r = __builtin_amdgcn_rcpf(e + 1.0f);
    return 1.0f - 2.0f * r;
#else
    return tanhf(x);
#endif
}

// ---------------------------------------------------------------------------
// Kernel 1: alignment scan -> jbuf.
// cond (src_len >= i - inserted) is provably always true for T<=S, so
// inserted == inclusive prefix sum of isin(tok,{1,2}) over positions 1..t.
// ---------------------------------------------------------------------------
__global__ void align_kernel(const int* __restrict__ iv, int* __restrict__ jbuf) {
    const int b = blockIdx.x;          // 32 blocks x 64 threads
    const int lane = threadIdx.x;      // 16 tokens per lane
    const int* row = iv + b * T_;
    int f[16];
    int local = 0;
    const int t0 = lane * 16;
    #pragma unroll
    for (int q = 0; q < 16; ++q) {
        const int t = t0 + q;
        const int tok = row[t];
        const int fl = (t > 0 && (tok == 1 || tok == 2)) ? 1 : 0;
        f[q] = fl;
        local += fl;
    }
    int incl = local;
    #pragma unroll
    for (int off = 1; off < 64; off <<= 1) {
        const int up = __shfl_up(incl, off, 64);
        if (lane >= off) incl += up;
    }
    int run = incl - local;            // exclusive prefix at this lane's first token
    #pragma unroll
    for (int q = 0; q < 16; ++q) {
        const int t = t0 + q;
        run += f[q];
        int j;
        if (t == 0) {
            j = 0;                     // attn[b,0,0] = 1 always
        } else {
            j = t - run - 1;
            if (j < 0) j += S_;        // torch negative-index wrap
        }
        jbuf[b * T_ + t] = j;
    }
}

// ---------------------------------------------------------------------------
// Kernel 2: W [512,1024] f32 -> bf16
// ---------------------------------------------------------------------------
__global__ void pack_w(const float* __restrict__ W, unsigned short* __restrict__ Wbf) {
    const int idx = blockIdx.x * blockDim.x + threadIdx.x;   // N_*K_/8 threads
    const f32x4 a = ((const f32x4*)W)[idx * 2];
    const f32x4 c = ((const f32x4*)W)[idx * 2 + 1];
    union { bf16x8 v; unsigned u[4]; } pk;
    pk.u[0] = cvt2bf(a[0], a[1]); pk.u[1] = cvt2bf(a[2], a[3]);
    pk.u[2] = cvt2bf(c[0], c[1]); pk.u[3] = cvt2bf(c[2], c[3]);
    *(bf16x8*)(Wbf + (size_t)idx * 8) = pk.v;
}

// ---------------------------------------------------------------------------
// Kernel 3 (heterogeneous): blocks [0,512) = attn one-hot (streaming, no LDS,
// dispatched FIRST so they co-run under GEMM); [512, 512+1024) = GEMM tiles.
//
// GEMM K-loop per iteration (the R4->R5 fix):
//   1. issue all 8 A-source f32x4 loads (k-contiguous chunk assignment:
//      8 lanes cover one row's 256B contiguously -> ~4x fewer line txns than
//      the R4 lane-stride-128B pattern)
//   2. issue B global_load_lds x4 (DMA, no VGPR result)
//   3. wait A only (compiler emits vmcnt(4)), cvt -> swizzled ds_write_b128 x4
//   4. barrier (drains B DMA + LDS), MFMA phase, barrier
// A-latency and B-latency now overlap instead of serializing.
//
// LDS XOR swizzle: k-chunk q (8 bf16=16B) of tile row r lives at slot
// r*8 + (q ^ (r&7)) -> fragment ds_read_b128 spreads all 8 bank groups.
// ---------------------------------------------------------------------------
#define BM 128
#define BN 128
#define BK 64
#define NGEMM ((M_ / BM) * (N_ / BN))   // 1024
#define NATTN 512                        // 64 rows each

__global__ __launch_bounds__(256, 4)
void gemm_attn(const unsigned short* __restrict__ Wbf,
               const float* __restrict__ bias,
               float* __restrict__ out,
               float* __restrict__ attn,
               const float* __restrict__ ctx,
               const float* __restrict__ outp,
               const int* __restrict__ jbuf) {
    const int bx = blockIdx.x;
    const int tid = threadIdx.x;

    if (bx < NATTN) {
        // ---------------- attn one-hot: 64 rows per block ----------------
        const int m0 = bx * 64;
        #pragma unroll 4
        for (int r = 0; r < 64; ++r) {
            const int row = m0 + r;
            const int j = jbuf[row];               // broadcast load
            f32x4 v = {0.f, 0.f, 0.f, 0.f};
            if ((j >> 2) == tid) v[j & 3] = 1.0f;
            ((f32x4*)(attn + (size_t)row * S_))[tid] = v;
        }
        return;
    }

    // ---------------- GEMM tile ----------------
    __shared__ unsigned short As[BM * BK];   // 16 KB
    __shared__ unsigned short Bs[BN * BK];   // 16 KB

    const int gbx  = bx - NATTN;
    const int lane = tid & 63;
    const int wave = tid >> 6;
    const int wm = wave >> 1, wn = wave & 1;     // 2x2 waves -> 64x64 each
    const int l16 = lane & 15, quad = lane >> 4;

    const int bm = gbx & 255;                    // 256 m-tiles (XCD-affine)
    const int bn = gbx >> 8;                     // 4 n-tiles
    const int mBase = bm * BM;
    const int nBase = bn * BN;

    // A staging: chunk c = it*256+tid, row = c>>3 = it*32 + (tid>>3),
    // kc = c&7 = tid&7 (fixed). Input: 8 f32 (32B) at src_row + ko + kc*8.
    const int kc   = tid & 7;
    const int rsub = tid >> 3;                   // 0..31
    const int sw   = kc ^ (rsub & 7);            // swizzle term, it-invariant
    const float* actx[4];
    const float* aout[4];
    #pragma unroll
    for (int it = 0; it < 4; ++it) {
        const int r = it * 32 + rsub;
        const int m = mBase + r;
        const int jm = jbuf[m];
        actx[it] = ctx + ((size_t)((m >> 10) * S_ + jm)) * D_ + kc * 8;
        aout[it] = outp + (size_t)m * D_ - D_ + kc * 8;     // add ko>=512
    }

    f32x4 acc[4][4] = {};

    for (int ko = 0; ko < K_; ko += BK) {
        // ---- 1. issue A loads (8 x f32x4, k-contiguous per row)
        f32x4 fa[4][2];
        #pragma unroll
        for (int it = 0; it < 4; ++it) {
            const float* src = (ko < D_) ? (actx[it] + ko) : (aout[it] + ko);
            fa[it][0] = ((const f32x4*)src)[0];
            fa[it][1] = ((const f32x4*)src)[1];
        }
        // ---- 2. issue B DMA (outstanding across the cvt)
        #pragma unroll
        for (int it = 0; it < 4; ++it) {
            const int chunk = it * 256 + tid;
            const int row = chunk >> 3;
            const int kcb = chunk & 7;
            const int gk8 = (kcb ^ (row & 7)) * 8;
            const unsigned short* gB = Wbf + (size_t)(nBase + row) * K_ + ko + gk8;
            __builtin_amdgcn_global_load_lds(
                (const __attribute__((address_space(1))) void*)gB,
                (__attribute__((address_space(3))) void*)(Bs + chunk * 8), 16, 0, 0);
        }
        // ---- 3. cvt + swizzled ds_write_b128 (waits A loads only)
        #pragma unroll
        for (int it = 0; it < 4; ++it) {
            union { bf16x8 v; unsigned u[4]; } pk;
            pk.u[0] = cvt2bf(fa[it][0][0], fa[it][0][1]);
            pk.u[1] = cvt2bf(fa[it][0][2], fa[it][0][3]);
            pk.u[2] = cvt2bf(fa[it][1][0], fa[it][1][1]);
            pk.u[3] = cvt2bf(fa[it][1][2], fa[it][1][3]);
            *(bf16x8*)&As[(it * 256 + rsub * 8 + sw) * 8] = pk.v;
        }
        __syncthreads();

        // ---- 4. MFMA phase: 2 K-steps of 32; 16 MFMA each
        #pragma unroll
        for (int ks = 0; ks < 2; ++ks) {
            bf16x8 af[4], bfr[4];
            #pragma unroll
            for (int mt = 0; mt < 4; ++mt) {
                const int r = wm * 64 + mt * 16 + l16;
                const int q = ks * 4 + quad;
                af[mt] = *(const bf16x8*)&As[(r * 8 + (q ^ (r & 7))) * 8];
            }
            #pragma unroll
            for (int nt = 0; nt < 4; ++nt) {
                const int r = wn * 64 + nt * 16 + l16;
                const int q = ks * 4 + quad;
                bfr[nt] = *(const bf16x8*)&Bs[(r * 8 + (q ^ (r & 7))) * 8];
            }
            #pragma unroll
            for (int mt = 0; mt < 4; ++mt)
                #pragma unroll
                for (int nt = 0; nt < 4; ++nt)
                    acc[mt][nt] = __builtin_amdgcn_mfma_f32_16x16x32_bf16(
                        af[mt], bfr[nt], acc[mt][nt], 0, 0, 0);
        }
        __syncthreads();
    }

    // ---- epilogue: fast_tanh(acc + bias), fp32 store
    #pragma unroll
    for (int nt = 0; nt < 4; ++nt) {
        const int n = nBase + wn * 64 + nt * 16 + l16;
        const float bv = bias[n];
        #pragma unroll
        for (int mt = 0; mt < 4; ++mt) {
            #pragma unroll
            for (int r = 0; r < 4; ++r) {
                const int m = mBase + wm * 64 + mt * 16 + quad * 4 + r;
                out[(size_t)m * N_ + n] = fast_tanh(acc[mt][nt][r] + bv);
            }
        }
    }
}

// ---------------------------------------------------------------------------
extern "C" void kernel_launch(void* const* d_in, const int* in_sizes, int n_in,
                              void* d_out, int out_size, void* d_ws, size_t ws_size,
                              hipStream_t stream) {
    const int*   iv   = (const int*)d_in[0];    // input_var [B,T]
    const float* outp = (const float*)d_in[1];  // output   [B,T,D]
    const float* ctx  = (const float*)d_in[2];  // context  [B,S,D]
    // d_in[3] = di (unused by reference body)
    const float* W    = (const float*)d_in[4];  // [D, 2D]
    const float* bias = (const float*)d_in[5];  // [D]

    float* out  = (float*)d_out;                       // [B,T,D]
    float* attn = out + (size_t)M_ * N_;               // [B,T,S]

    // workspace layout: j[M_] int32 | Wbf[N_*K_] bf16   (~1.1 MB total)
    int* jbuf = (int*)d_ws;
    unsigned short* Wbf = (unsigned short*)((char*)d_ws + (size_t)M_ * 4);

    align_kernel<<<B_, 64, 0, stream>>>(iv, jbuf);
    pack_w<<<(N_ * K_ / 8) / 256, 256, 0, stream>>>(W, Wbf);
    gemm_attn<<<NGEMM + NATTN, 256, 0, stream>>>(Wbf, bias, out, attn, ctx, outp, jbuf);
}